// Round 6
// baseline (95.993 us; speedup 1.0000x reference)
//
#include <hip/hip_runtime.h>
#include <hip/hip_bf16.h>

#define NSPLIT 16
#define BIGF 1e30f
#define MARGIN 0.3f
#define DK 128

typedef __attribute__((ext_vector_type(8))) short bf16x8;
typedef __attribute__((ext_vector_type(4))) float f32x4;

// workspace word offsets
#define WS_HIST 0                  // 1024 u32 label histogram       (memset)
#define WS_GSUM 1024               // f32 sum                        (memset)
#define WS_GCNT 1025               // f32 cnt                        (memset)
#define WS_BCNT 1026               // u32 block counter              (memset)
#define WS_HP   1028               // 8192 u32 max d2_pos bits       (init by prep)
#define WS_HN   (WS_HP + 8192)     // 8192 u32 max ~d2_neg bits      (init by prep)
#define WS_SQ   (WS_HN + 8192)     // 8192 f32 squared norms         (written by prep)
#define WS_XB   (WS_SQ + 8192)     // bf16 copy of X, fragment-swizzled (16B aligned)
#define WS_ZERO_BYTES (1028 * 4)   // only hist + scalars need the memset

// Fragment-swizzled bf16 layout of X:
//   xs[ (row>>4)*2048 + (k>>3)*128 + (row&15)*8 + (k&7) ]
// An MFMA A/B fragment load (16 rows, k = s*32+quad*8..+7) is 64 lanes reading
// ONE CONTIGUOUS 1KB block -> coalesced global_load_dwordx4.

// Kernel 1: swizzled bf16 copy + fp32 squared norms + label histogram
// + zero-init of the per-row hp/hn atomics slots. (unchanged)
__global__ __launch_bounds__(256) void prep_kernel(
    const float* __restrict__ x, ushort* __restrict__ xs,
    float* __restrict__ sq, unsigned* __restrict__ hist,
    const int* __restrict__ lab,
    unsigned* __restrict__ hp_bits, unsigned* __restrict__ hn_comp, int N)
{
    const int tid = threadIdx.x;
    const int rbase = blockIdx.x * 32;
    const int rl = tid >> 4;           // row within 16-row group (0..15)
    const int kc = tid & 15;           // 8-elem k-chunk (0..15)

    #pragma unroll
    for (int g = 0; g < 2; ++g) {
        int row = rbase + g * 16 + rl;
        const float4* p = (const float4*)(x + (size_t)row * DK + kc * 8);
        float4 u = p[0], v = p[1];
        float f[8] = {u.x, u.y, u.z, u.w, v.x, v.y, v.z, v.w};
        union { bf16x8 v8; ushort us[8]; } o;
        float ps = 0.0f;
        #pragma unroll
        for (int e = 0; e < 8; ++e) {
            __hip_bfloat16 b = __float2bfloat16(f[e]);
            o.us[e] = *(ushort*)&b;
            ps += f[e] * f[e];
        }
        ((bf16x8*)xs)[(size_t)(row >> 4) * 256 + kc * 16 + rl] = o.v8;
        #pragma unroll
        for (int o2 = 8; o2 > 0; o2 >>= 1) ps += __shfl_xor(ps, o2, 16);
        if (kc == 0) {
            sq[row] = ps;
            hp_bits[row] = 0u;             // identity for max(d2p>=0)
            hn_comp[row] = 0u;             // ~bits identity for min-complement
            atomicAdd(&hist[lab[row]], 1u);
        }
    }
}

// ---- tile_kernel helpers ------------------------------------------------

// Load one 16-col B chunk: 4 coalesced b128 frag loads + 1 sq + 1 lab.
#define LOADB(B, SQB, LB, CH)                                             \
    {                                                                     \
        const unsigned cb = (unsigned)cbegin + (unsigned)(CH) * 16;       \
        const ushort* bp = xs + (size_t)cb * DK + quad * 128 + m16 * 8;   \
        _Pragma("unroll")                                                 \
        for (int s = 0; s < 4; ++s)                                       \
            B[s] = *(const bf16x8*)(bp + s * 512);                        \
        int colg = (int)cb + m16;                                         \
        SQB = sq[colg]; LB = lab[colg];                                   \
    }

// 8 MFMAs for one 32x16 output chunk; C=0 folded into s=0.
#define MFMA_CHUNK(B)                                                     \
    _Pragma("unroll")                                                     \
    for (int s = 0; s < 4; ++s)                                           \
        _Pragma("unroll")                                                 \
        for (int mt = 0; mt < 2; ++mt)                                    \
            acc[mt] = __builtin_amdgcn_mfma_f32_16x16x32_bf16(            \
                afr[mt][s], B[s],                                         \
                (s == 0) ? (f32x4){0.f, 0.f, 0.f, 0.f} : acc[mt],         \
                0, 0, 0);

// masked max/min epilogue for one chunk (2mt x 4r = 8 outputs/lane).
#define EPI_CHUNK(SQB, LB)                                                \
    _Pragma("unroll")                                                     \
    for (int mt = 0; mt < 2; ++mt)                                        \
        _Pragma("unroll")                                                 \
        for (int r = 0; r < 4; ++r) {                                     \
            float t = fmaf(-2.0f, acc[mt][r], SQB);                       \
            bool sm = (rlv[mt][r] == LB);                                 \
            runhp[mt][r] = fmaxf(runhp[mt][r], sm ? t : -BIGF);           \
            runhn[mt][r] = fminf(runhn[mt][r], sm ? BIGF : t);            \
        }

// Kernel 2: fused bf16-MFMA dist^2 tile + masked max/min in t = sqb - 2*dot.
// LDS-free, barrier-free: each wave owns 32 rows x the full 512-col split;
// A-fragments (32 VGPR) global-loaded once, reused 32x. B streams in 16-col
// chunks (4 b128 loads), double-buffered one chunk deep (16+16 regs).
// VGPR diet vs round 5 (which peaked ~156 and silently dropped to 2-3
// waves/SIMD): peak live ~ afr32 + b32 + acc8 + runh16 + rlv8 + misc ~16
// = ~112 -> __launch_bounds__(256,4) caps at 128 WITHOUT spilling and
// guarantees 4 waves/SIMD, 4 blocks/CU (1024 blocks = 1 residency wave).
// Floor: per-CU B streaming ~2MB through L1/L2 ~= 13-16 us.
__global__ __launch_bounds__(256, 4) void tile_kernel(
    const ushort* __restrict__ xs, const float* __restrict__ sq,
    const int* __restrict__ lab,
    unsigned* __restrict__ hp_bits, unsigned* __restrict__ hn_comp, int N)
{
    const int tid  = threadIdx.x;
    const int lane = tid & 63;
    const int wave = tid >> 6;
    const int m16  = lane & 15;
    const int quad = lane >> 4;
    const int rbase  = blockIdx.x * 128 + wave * 32;
    const int cbegin = blockIdx.y * (N / NSPLIT);

    // A fragments: registers for the whole kernel (reused 32x)
    bf16x8 afr[2][4];
    {
        const ushort* ap = xs + (size_t)rbase * DK + quad * 128 + m16 * 8;
        #pragma unroll
        for (int mt = 0; mt < 2; ++mt)
            #pragma unroll
            for (int s = 0; s < 4; ++s)
                afr[mt][s] = *(const bf16x8*)(ap + mt * 2048 + s * 512);
    }

    // row labels for this lane's 8 output rows (broadcast int4 loads)
    int rlv[2][4];
    #pragma unroll
    for (int mt = 0; mt < 2; ++mt) {
        int4 v = *(const int4*)(lab + rbase + mt * 16 + quad * 4);
        rlv[mt][0] = v.x; rlv[mt][1] = v.y; rlv[mt][2] = v.z; rlv[mt][3] = v.w;
    }

    float runhp[2][4], runhn[2][4];
    #pragma unroll
    for (int mt = 0; mt < 2; ++mt)
        #pragma unroll
        for (int r = 0; r < 4; ++r) { runhp[mt][r] = -BIGF; runhn[mt][r] = BIGF; }

    bf16x8 bX[4], bY[4];
    float sqX, sqY;
    int lbX, lbY;
    f32x4 acc[2];

    LOADB(bX, sqX, lbX, 0);

    // 32 chunks of 16 cols; 2-chunk unrolled body, all indexing static.
    #pragma unroll 1
    for (int k = 0; k < 32; k += 2) {
        LOADB(bY, sqY, lbY, k + 1);          // in flight under MFMA+EPI of bX
        MFMA_CHUNK(bX);
        EPI_CHUNK(sqX, lbX);
        LOADB(bX, sqX, lbX, (k + 2 < 32) ? k + 2 : 31);  // clamped: dead on last
        MFMA_CHUNK(bY);
        EPI_CHUNK(sqY, lbY);
    }

    // reduce across the 16 m16-lanes (cols) sharing each row
    #pragma unroll
    for (int mt = 0; mt < 2; ++mt)
        #pragma unroll
        for (int r = 0; r < 4; ++r) {
            #pragma unroll
            for (int o = 8; o > 0; o >>= 1) {
                runhp[mt][r] = fmaxf(runhp[mt][r], __shfl_xor(runhp[mt][r], o, 16));
                runhn[mt][r] = fminf(runhn[mt][r], __shfl_xor(runhn[mt][r], o, 16));
            }
        }

    if (m16 == 0) {
        #pragma unroll
        for (int mt = 0; mt < 2; ++mt)
            #pragma unroll
            for (int r = 0; r < 4; ++r) {
                int row = rbase + mt * 16 + quad * 4 + r;
                float sqa = sq[row];
                float d2p = fmaxf(sqa + runhp[mt][r], 0.0f);  // == ref's max(d2,0)
                float d2n = fmaxf(sqa + runhn[mt][r], 0.0f);
                atomicMax(&hp_bits[row], __float_as_uint(d2p));
                atomicMax(&hn_comp[row], ~__float_as_uint(d2n));  // min via complement
            }
    }
}

// Kernel 3: per-row loss + grid reduction; last block writes the scalar.
__global__ void finalize_kernel(const unsigned* __restrict__ hp_bits,
                                const unsigned* __restrict__ hn_comp,
                                const int* __restrict__ lab,
                                const unsigned* __restrict__ hist,
                                float* __restrict__ gsum, float* __restrict__ gcnt,
                                unsigned* __restrict__ bcount,
                                float* __restrict__ out, int N)
{
    __shared__ float s_sum[256];
    __shared__ float s_cnt[256];
    int tid = threadIdx.x;
    int row = blockIdx.x * 256 + tid;
    float loss = 0.0f, cv = 0.0f;
    if (row < N) {
        unsigned c = hist[lab[row]];
        bool valid = (c >= 2u) && (c < (unsigned)N);
        if (valid) {
            float dp = sqrtf(__uint_as_float(hp_bits[row]));
            float dn = sqrtf(__uint_as_float(~hn_comp[row]));
            loss = fmaxf(dp - dn + MARGIN, 0.0f);
            cv = 1.0f;
        }
    }
    s_sum[tid] = loss; s_cnt[tid] = cv;
    __syncthreads();
    for (int o = 128; o > 0; o >>= 1) {
        if (tid < o) { s_sum[tid] += s_sum[tid + o]; s_cnt[tid] += s_cnt[tid + o]; }
        __syncthreads();
    }
    if (tid == 0) {
        atomicAdd(gsum, s_sum[0]);
        atomicAdd(gcnt, s_cnt[0]);
        __threadfence();
        unsigned old = atomicAdd(bcount, 1u);
        if (old == gridDim.x - 1) {
            float s = atomicAdd(gsum, 0.0f);   // coherent read
            float c = atomicAdd(gcnt, 0.0f);
            out[0] = (c > 0.0f) ? s / c : 0.0f;
        }
    }
}

extern "C" void kernel_launch(void* const* d_in, const int* in_sizes, int n_in,
                              void* d_out, int out_size, void* d_ws, size_t ws_size,
                              hipStream_t stream) {
    const float* x = (const float*)d_in[0];
    const int* lab = (const int*)d_in[1];
    float* out = (float*)d_out;
    const int N = in_sizes[1];          // 8192

    unsigned* ws = (unsigned*)d_ws;
    unsigned* hist    = ws + WS_HIST;
    float* gsum = (float*)(ws + WS_GSUM);
    float* gcnt = (float*)(ws + WS_GCNT);
    unsigned* bcount = ws + WS_BCNT;
    unsigned* hp_bits = ws + WS_HP;
    unsigned* hn_comp = ws + WS_HN;
    float* sq = (float*)(ws + WS_SQ);
    ushort* xs = (ushort*)(ws + WS_XB);

    hipMemsetAsync(d_ws, 0, (size_t)WS_ZERO_BYTES, stream);
    prep_kernel<<<N / 32, 256, 0, stream>>>(x, xs, sq, hist, lab, hp_bits, hn_comp, N);
    dim3 grid(N / 128, NSPLIT);
    tile_kernel<<<grid, 256, 0, stream>>>(xs, sq, lab, hp_bits, hn_comp, N);
    finalize_kernel<<<N / 256, 256, 0, stream>>>(hp_bits, hn_comp, lab, hist,
                                                 gsum, gcnt, bcount, out, N);
}

// Round 7
// 95.233 us; speedup vs baseline: 1.0080x; 1.0080x over previous
//
#include <hip/hip_runtime.h>
#include <hip/hip_bf16.h>

#define BIGF 1e30f
#define MARGIN 0.3f
#define DK 128

typedef __attribute__((ext_vector_type(8))) short bf16x8;
typedef __attribute__((ext_vector_type(4))) float f32x4;

// workspace word offsets
#define WS_HIST 0                  // 1024 u32 label histogram       (memset)
#define WS_GSUM 1024               // f32 sum                        (memset)
#define WS_GCNT 1025               // f32 cnt                        (memset)
#define WS_BCNT 1026               // u32 block counter              (memset)
#define WS_HP   1028               // 8192 u32 max d2_pos bits       (init by prep)
#define WS_HN   (WS_HP + 8192)     // 8192 u32 max ~d2_neg bits      (init by prep)
#define WS_SQ   (WS_HN + 8192)     // 8192 f32 squared norms         (written by prep)
#define WS_XB   (WS_SQ + 8192)     // bf16 copy of X, fragment-swizzled (16B aligned)
#define WS_ZERO_BYTES (1028 * 4)   // only hist + scalars need the memset

// Fragment-swizzled bf16 layout of X:
//   xs[ (row>>4)*2048 + (k>>3)*128 + (row&15)*8 + (k&7) ]
// An MFMA A/B fragment load (16 rows, k = s*32+quad*8..+7) is 64 lanes reading
// ONE CONTIGUOUS 1KB block -> coalesced global_load_dwordx4.

// Kernel 1: swizzled bf16 copy + fp32 squared norms + label histogram
// + zero-init of the per-row hp/hn atomics slots. (unchanged)
__global__ __launch_bounds__(256) void prep_kernel(
    const float* __restrict__ x, ushort* __restrict__ xs,
    float* __restrict__ sq, unsigned* __restrict__ hist,
    const int* __restrict__ lab,
    unsigned* __restrict__ hp_bits, unsigned* __restrict__ hn_comp, int N)
{
    const int tid = threadIdx.x;
    const int rbase = blockIdx.x * 32;
    const int rl = tid >> 4;           // row within 16-row group (0..15)
    const int kc = tid & 15;           // 8-elem k-chunk (0..15)

    #pragma unroll
    for (int g = 0; g < 2; ++g) {
        int row = rbase + g * 16 + rl;
        const float4* p = (const float4*)(x + (size_t)row * DK + kc * 8);
        float4 u = p[0], v = p[1];
        float f[8] = {u.x, u.y, u.z, u.w, v.x, v.y, v.z, v.w};
        union { bf16x8 v8; ushort us[8]; } o;
        float ps = 0.0f;
        #pragma unroll
        for (int e = 0; e < 8; ++e) {
            __hip_bfloat16 b = __float2bfloat16(f[e]);
            o.us[e] = *(ushort*)&b;
            ps += f[e] * f[e];
        }
        ((bf16x8*)xs)[(size_t)(row >> 4) * 256 + kc * 16 + rl] = o.v8;
        #pragma unroll
        for (int o2 = 8; o2 > 0; o2 >>= 1) ps += __shfl_xor(ps, o2, 16);
        if (kc == 0) {
            sq[row] = ps;
            hp_bits[row] = 0u;             // identity for max(d2p>=0)
            hn_comp[row] = 0u;             // ~bits identity for min-complement
            atomicAdd(&hist[lab[row]], 1u);
        }
    }
}

// ---- tile_kernel helpers ------------------------------------------------

// Load one 16-col B chunk: 4 coalesced b128 frag loads + 1 sq + 1 lab.
#define LOADB(B, SQB, LB, CH)                                             \
    {                                                                     \
        const unsigned cb = (unsigned)cbase + (unsigned)(CH) * 16;        \
        const ushort* bp = xs + (size_t)cb * DK + quad * 128 + m16 * 8;   \
        _Pragma("unroll")                                                 \
        for (int s = 0; s < 4; ++s)                                       \
            B[s] = *(const bf16x8*)(bp + s * 512);                        \
        int colg = (int)cb + m16;                                         \
        SQB = sq[colg]; LB = lab[colg];                                   \
    }

// 8 MFMAs for one 32x16 output chunk; C=0 folded into s=0.
#define MFMA_CHUNK(B)                                                     \
    _Pragma("unroll")                                                     \
    for (int s = 0; s < 4; ++s)                                           \
        _Pragma("unroll")                                                 \
        for (int mt = 0; mt < 2; ++mt)                                    \
            acc[mt] = __builtin_amdgcn_mfma_f32_16x16x32_bf16(            \
                afr[mt][s], B[s],                                         \
                (s == 0) ? (f32x4){0.f, 0.f, 0.f, 0.f} : acc[mt],         \
                0, 0, 0);

// Dual-sided epilogue: each dot feeds the ROW update (t = sq_col - 2dot ->
// runhp/hn for this wave's rows) AND the COL update (tc = sq_row - 2dot ->
// per-col partials, reduced over the wave's 32 rows via in-lane r-fold +
// shfl_xor over the quad bits, parked in LDS for cross-wave combine).
#define EPI_CHUNK(CH, SQB, LB)                                            \
    {                                                                     \
        float cph = -BIGF, cnh = BIGF;                                    \
        _Pragma("unroll")                                                 \
        for (int mt = 0; mt < 2; ++mt)                                    \
            _Pragma("unroll")                                             \
            for (int r = 0; r < 4; ++r) {                                 \
                float d = acc[mt][r];                                     \
                float t  = fmaf(-2.0f, d, SQB);                           \
                float tc = fmaf(-2.0f, d, sqa[mt][r]);                    \
                bool sm = (rlv[mt][r] == LB);                             \
                runhp[mt][r] = fmaxf(runhp[mt][r], sm ? t : -BIGF);       \
                runhn[mt][r] = fminf(runhn[mt][r], sm ? BIGF : t);        \
                cph = fmaxf(cph, sm ? tc : -BIGF);                        \
                cnh = fminf(cnh, sm ? BIGF : tc);                         \
            }                                                             \
        cph = fmaxf(cph, __shfl_xor(cph, 16, 64));                        \
        cph = fmaxf(cph, __shfl_xor(cph, 32, 64));                        \
        cnh = fminf(cnh, __shfl_xor(cnh, 16, 64));                        \
        cnh = fminf(cnh, __shfl_xor(cnh, 32, 64));                        \
        if (lane < 16) {                                                  \
            colhp_s[wave][(CH) * 16 + m16] = cph;                         \
            colhn_s[wave][(CH) * 16 + m16] = cnh;                         \
        }                                                                 \
    }

// Kernel 2: SYMMETRIC fused bf16-MFMA dist^2 + masked max/min.
// dist(i,j)=dist(j,i): each unordered 128x128 block pair is computed ONCE
// (grid (NB, NB/2+1), wrap mapping bj=(bi+by)%NB; the d=NB/2 pairs are
// double-covered -- harmless, max/min idempotent; diagonal contributes
// d2=0 to pos-max (identity) and is label-excluded from neg).
// Halves MFMA work (1.05M -> 541K) and B traffic (512 -> ~135 MB); unique
// B per block is 32 KB -> L1-resident, so 3 of 4 waves hit L1 (~30cy)
// instead of L2 (~200cy). Each wave: 32 rows x 128 cols, A-frags in regs,
// B double-buffered 16-col chunks. Col results cross-wave-combined in 4KB
// LDS after the loop (one barrier).
__global__ __launch_bounds__(256, 2) void tile_kernel(
    const ushort* __restrict__ xs, const float* __restrict__ sq,
    const int* __restrict__ lab,
    unsigned* __restrict__ hp_bits, unsigned* __restrict__ hn_comp, int N)
{
    __shared__ float colhp_s[4][128];
    __shared__ float colhn_s[4][128];

    const int tid  = threadIdx.x;
    const int lane = tid & 63;
    const int wave = tid >> 6;
    const int m16  = lane & 15;
    const int quad = lane >> 4;
    const int NB   = N >> 7;                       // 64 row/col blocks
    const int bi   = blockIdx.x;
    const int bj   = (int)((blockIdx.x + blockIdx.y) % (unsigned)NB);
    const int rbase = bi * 128 + wave * 32;
    const int cbase = bj * 128;

    // A fragments: registers for the whole kernel
    bf16x8 afr[2][4];
    {
        const ushort* ap = xs + (size_t)rbase * DK + quad * 128 + m16 * 8;
        #pragma unroll
        for (int mt = 0; mt < 2; ++mt)
            #pragma unroll
            for (int s = 0; s < 4; ++s)
                afr[mt][s] = *(const bf16x8*)(ap + mt * 2048 + s * 512);
    }

    // this lane's 8 row labels + row squared norms (broadcast 16B loads)
    int rlv[2][4]; float sqa[2][4];
    #pragma unroll
    for (int mt = 0; mt < 2; ++mt) {
        int4 v = *(const int4*)(lab + rbase + mt * 16 + quad * 4);
        rlv[mt][0] = v.x; rlv[mt][1] = v.y; rlv[mt][2] = v.z; rlv[mt][3] = v.w;
        float4 s4 = *(const float4*)(sq + rbase + mt * 16 + quad * 4);
        sqa[mt][0] = s4.x; sqa[mt][1] = s4.y; sqa[mt][2] = s4.z; sqa[mt][3] = s4.w;
    }

    float runhp[2][4], runhn[2][4];
    #pragma unroll
    for (int mt = 0; mt < 2; ++mt)
        #pragma unroll
        for (int r = 0; r < 4; ++r) { runhp[mt][r] = -BIGF; runhn[mt][r] = BIGF; }

    bf16x8 bX[4], bY[4];
    float sqX, sqY;
    int lbX, lbY;
    f32x4 acc[2];

    LOADB(bX, sqX, lbX, 0);

    // 8 chunks of 16 cols; 2-chunk body, all indexing static.
    #pragma unroll 1
    for (int k = 0; k < 8; k += 2) {
        LOADB(bY, sqY, lbY, k + 1);          // in flight under MFMA+EPI of bX
        MFMA_CHUNK(bX);
        EPI_CHUNK(k, sqX, lbX);
        LOADB(bX, sqX, lbX, (k + 2 < 8) ? k + 2 : 7);  // clamped: dead on last
        MFMA_CHUNK(bY);
        EPI_CHUNK(k + 1, sqY, lbY);
    }

    // row results: reduce across the 16 m16-lanes (cols) sharing each row
    #pragma unroll
    for (int mt = 0; mt < 2; ++mt)
        #pragma unroll
        for (int r = 0; r < 4; ++r) {
            #pragma unroll
            for (int o = 8; o > 0; o >>= 1) {
                runhp[mt][r] = fmaxf(runhp[mt][r], __shfl_xor(runhp[mt][r], o, 16));
                runhn[mt][r] = fminf(runhn[mt][r], __shfl_xor(runhn[mt][r], o, 16));
            }
        }

    if (m16 == 0) {
        #pragma unroll
        for (int mt = 0; mt < 2; ++mt)
            #pragma unroll
            for (int r = 0; r < 4; ++r) {
                int row = rbase + mt * 16 + quad * 4 + r;
                float d2p = fmaxf(sqa[mt][r] + runhp[mt][r], 0.0f);
                float d2n = fmaxf(sqa[mt][r] + runhn[mt][r], 0.0f);
                atomicMax(&hp_bits[row], __float_as_uint(d2p));
                atomicMax(&hn_comp[row], ~__float_as_uint(d2n));  // min via complement
            }
    }

    // col results: combine the 4 waves' partials, then atomics
    __syncthreads();
    if (tid < 128) {
        float thp = fmaxf(fmaxf(colhp_s[0][tid], colhp_s[1][tid]),
                          fmaxf(colhp_s[2][tid], colhp_s[3][tid]));
        float thn = fminf(fminf(colhn_s[0][tid], colhn_s[1][tid]),
                          fminf(colhn_s[2][tid], colhn_s[3][tid]));
        int col = cbase + tid;
        float sqc = sq[col];
        float d2p = fmaxf(sqc + thp, 0.0f);
        float d2n = fmaxf(sqc + thn, 0.0f);
        atomicMax(&hp_bits[col], __float_as_uint(d2p));
        atomicMax(&hn_comp[col], ~__float_as_uint(d2n));
    }
}

// Kernel 3: per-row loss + grid reduction; last block writes the scalar.
__global__ void finalize_kernel(const unsigned* __restrict__ hp_bits,
                                const unsigned* __restrict__ hn_comp,
                                const int* __restrict__ lab,
                                const unsigned* __restrict__ hist,
                                float* __restrict__ gsum, float* __restrict__ gcnt,
                                unsigned* __restrict__ bcount,
                                float* __restrict__ out, int N)
{
    __shared__ float s_sum[256];
    __shared__ float s_cnt[256];
    int tid = threadIdx.x;
    int row = blockIdx.x * 256 + tid;
    float loss = 0.0f, cv = 0.0f;
    if (row < N) {
        unsigned c = hist[lab[row]];
        bool valid = (c >= 2u) && (c < (unsigned)N);
        if (valid) {
            float dp = sqrtf(__uint_as_float(hp_bits[row]));
            float dn = sqrtf(__uint_as_float(~hn_comp[row]));
            loss = fmaxf(dp - dn + MARGIN, 0.0f);
            cv = 1.0f;
        }
    }
    s_sum[tid] = loss; s_cnt[tid] = cv;
    __syncthreads();
    for (int o = 128; o > 0; o >>= 1) {
        if (tid < o) { s_sum[tid] += s_sum[tid + o]; s_cnt[tid] += s_cnt[tid + o]; }
        __syncthreads();
    }
    if (tid == 0) {
        atomicAdd(gsum, s_sum[0]);
        atomicAdd(gcnt, s_cnt[0]);
        __threadfence();
        unsigned old = atomicAdd(bcount, 1u);
        if (old == gridDim.x - 1) {
            float s = atomicAdd(gsum, 0.0f);   // coherent read
            float c = atomicAdd(gcnt, 0.0f);
            out[0] = (c > 0.0f) ? s / c : 0.0f;
        }
    }
}

extern "C" void kernel_launch(void* const* d_in, const int* in_sizes, int n_in,
                              void* d_out, int out_size, void* d_ws, size_t ws_size,
                              hipStream_t stream) {
    const float* x = (const float*)d_in[0];
    const int* lab = (const int*)d_in[1];
    float* out = (float*)d_out;
    const int N = in_sizes[1];          // 8192

    unsigned* ws = (unsigned*)d_ws;
    unsigned* hist    = ws + WS_HIST;
    float* gsum = (float*)(ws + WS_GSUM);
    float* gcnt = (float*)(ws + WS_GCNT);
    unsigned* bcount = ws + WS_BCNT;
    unsigned* hp_bits = ws + WS_HP;
    unsigned* hn_comp = ws + WS_HN;
    float* sq = (float*)(ws + WS_SQ);
    ushort* xs = (ushort*)(ws + WS_XB);

    hipMemsetAsync(d_ws, 0, (size_t)WS_ZERO_BYTES, stream);
    prep_kernel<<<N / 32, 256, 0, stream>>>(x, xs, sq, hist, lab, hp_bits, hn_comp, N);
    const int NB = N / 128;                       // 64
    dim3 grid(NB, NB / 2 + 1);                    // unordered block pairs (wrap)
    tile_kernel<<<grid, 256, 0, stream>>>(xs, sq, lab, hp_bits, hn_comp, N);
    finalize_kernel<<<N / 256, 256, 0, stream>>>(hp_bits, hn_comp, lab, hist,
                                                 gsum, gcnt, bcount, out, N);
}

// Round 8
// 87.200 us; speedup vs baseline: 1.1008x; 1.0921x over previous
//
#include <hip/hip_runtime.h>
#include <hip/hip_bf16.h>

#define NSPLIT 8
#define BIGF 1e30f
#define MARGIN 0.3f
#define DK 128

typedef __attribute__((ext_vector_type(8))) short bf16x8;
typedef __attribute__((ext_vector_type(4))) float f32x4;

// workspace word offsets
#define WS_HIST 0                  // 1024 u32 label histogram  (zeroed by prep, filled by tile y==0)
#define WS_GSUM 1024               // f32 sum                   (zeroed by prep)
#define WS_GCNT 1025               // f32 cnt                   (zeroed by prep)
#define WS_BCNT 1026               // u32 block counter         (zeroed by prep)
#define WS_HP   1028               // 8192 u32 max d2_pos bits  (init by prep)
#define WS_HN   (WS_HP + 8192)     // 8192 u32 max ~d2_neg bits (init by prep)
#define WS_SQ   (WS_HN + 8192)     // 8192 f32 squared norms    (written by prep)
#define WS_XB   (WS_SQ + 8192)     // bf16 copy of X, fragment-swizzled (16B aligned)

// Fragment-swizzled bf16 layout of X:
//   xs[ (row>>4)*2048 + (k>>3)*128 + (row&15)*8 + (k&7) ]
// An MFMA A/B fragment load (16 rows, k = s*32+quad*8..+7) is 64 lanes reading
// ONE CONTIGUOUS 1KB block -> coalesced global_load_dwordx4.

// Kernel 1: swizzled bf16 copy + fp32 squared norms + zero-init of hist,
// scalars, and per-row hp/hn atomic slots. NO memset dispatch needed:
// hist accumulation moved to tile (y==0 blocks), so prep may zero it here
// (kernel boundary orders prep-writes before tile-reads).
__global__ __launch_bounds__(256) void prep_kernel(
    const float* __restrict__ x, ushort* __restrict__ xs,
    float* __restrict__ sq, unsigned* __restrict__ hist,
    unsigned* __restrict__ scal,
    unsigned* __restrict__ hp_bits, unsigned* __restrict__ hn_comp, int N)
{
    const int tid = threadIdx.x;
    const int rbase = blockIdx.x * 32;
    const int rl = tid >> 4;           // row within 16-row group (0..15)
    const int kc = tid & 15;           // 8-elem k-chunk (0..15)

    // fold the old hipMemsetAsync into prep: 256 blocks x 4 hist entries
    if (tid < 4) {
        hist[blockIdx.x * 4 + tid] = 0u;
        if (blockIdx.x == 0) scal[tid] = 0u;   // gsum, gcnt, bcount, pad
    }

    #pragma unroll
    for (int g = 0; g < 2; ++g) {
        int row = rbase + g * 16 + rl;
        const float4* p = (const float4*)(x + (size_t)row * DK + kc * 8);
        float4 u = p[0], v = p[1];
        float f[8] = {u.x, u.y, u.z, u.w, v.x, v.y, v.z, v.w};
        union { bf16x8 v8; ushort us[8]; } o;
        float ps = 0.0f;
        #pragma unroll
        for (int e = 0; e < 8; ++e) {
            __hip_bfloat16 b = __float2bfloat16(f[e]);
            o.us[e] = *(ushort*)&b;
            ps += f[e] * f[e];
        }
        ((bf16x8*)xs)[(size_t)(row >> 4) * 256 + kc * 16 + rl] = o.v8;
        #pragma unroll
        for (int o2 = 8; o2 > 0; o2 >>= 1) ps += __shfl_xor(ps, o2, 16);
        if (kc == 0) {
            sq[row] = ps;
            hp_bits[row] = 0u;             // identity for max(d2p>=0)
            hn_comp[row] = 0u;             // ~bits identity for min-complement
        }
    }
}

// ---- tile_kernel helpers ------------------------------------------------

// Load one 32-col B chunk: 8 coalesced b128 frag loads + 2 sq + 2 lab.
#define LOADB(B, SQB, LB, CH)                                             \
    {                                                                     \
        const unsigned cb = (unsigned)cbegin + (unsigned)(CH) * 32;       \
        const ushort* bp = xs + (size_t)cb * DK + quad * 128 + m16 * 8;   \
        _Pragma("unroll")                                                 \
        for (int nt = 0; nt < 2; ++nt)                                    \
            _Pragma("unroll")                                             \
            for (int s = 0; s < 4; ++s)                                   \
                B[nt * 4 + s] = *(const bf16x8*)(bp + nt * 2048 + s * 512); \
        _Pragma("unroll")                                                 \
        for (int nt = 0; nt < 2; ++nt) {                                  \
            int colg = (int)cb + nt * 16 + m16;                           \
            SQB[nt] = sq[colg]; LB[nt] = lab[colg];                       \
        }                                                                 \
    }

// 16 MFMAs for one 32x32 output chunk; C=0 folded into s=0.
#define MFMA_CHUNK(B)                                                     \
    _Pragma("unroll")                                                     \
    for (int s = 0; s < 4; ++s)                                           \
        _Pragma("unroll")                                                 \
        for (int mt = 0; mt < 2; ++mt)                                    \
            _Pragma("unroll")                                             \
            for (int nt = 0; nt < 2; ++nt)                                \
                acc[mt][nt] = __builtin_amdgcn_mfma_f32_16x16x32_bf16(    \
                    afr[mt][s], B[nt * 4 + s],                            \
                    (s == 0) ? (f32x4){0.f, 0.f, 0.f, 0.f} : acc[mt][nt], \
                    0, 0, 0);

// masked max/min epilogue; fmaxf(fmaxf(.,.),.) fuses to v_max3/min3.
#define EPI_CHUNK(SQB, LB)                                                \
    _Pragma("unroll")                                                     \
    for (int mt = 0; mt < 2; ++mt)                                        \
        _Pragma("unroll")                                                 \
        for (int r = 0; r < 4; ++r) {                                     \
            int rl = rlv[mt][r];                                          \
            float t0 = fmaf(-2.0f, acc[mt][0][r], SQB[0]);                \
            float t1 = fmaf(-2.0f, acc[mt][1][r], SQB[1]);                \
            bool s0 = (rl == LB[0]);                                      \
            bool s1 = (rl == LB[1]);                                      \
            runhp[mt][r] = fmaxf(fmaxf(runhp[mt][r], s0 ? t0 : -BIGF),    \
                                 s1 ? t1 : -BIGF);                        \
            runhn[mt][r] = fminf(fminf(runhn[mt][r], s0 ? BIGF : t0),     \
                                 s1 ? BIGF : t1);                         \
        }

// Kernel 2: fused bf16-MFMA dist^2 tile + masked max/min in t = sqb - 2*dot.
// Round-5 structure (best measured): LDS-free, barrier-free, each wave owns
// 32 rows x the full split; A-frags in regs (reused), B streamed in 32-col
// chunks double-buffered. NSPLIT=8: 512 blocks = EXACTLY one residency
// generation at the measured 2 blocks/CU (~152 VGPR -> 2 waves/SIMD), and
// halves per-block fixed costs (A-load latency, setup, atomics) vs NSPLIT=16.
// y==0 blocks also build the label histogram (each row counted once).
__global__ __launch_bounds__(256, 2) void tile_kernel(
    const ushort* __restrict__ xs, const float* __restrict__ sq,
    const int* __restrict__ lab, unsigned* __restrict__ hist,
    unsigned* __restrict__ hp_bits, unsigned* __restrict__ hn_comp, int N)
{
    const int tid  = threadIdx.x;
    const int lane = tid & 63;
    const int wave = tid >> 6;
    const int m16  = lane & 15;
    const int quad = lane >> 4;
    const int rbase  = blockIdx.x * 128 + wave * 32;
    const int cbegin = blockIdx.y * (N / NSPLIT);

    // label histogram: each block-row counted once, by its y==0 block
    if (blockIdx.y == 0 && tid < 128)
        atomicAdd(&hist[lab[blockIdx.x * 128 + tid]], 1u);

    // A fragments: registers for the whole kernel (reused 32x)
    bf16x8 afr[2][4];
    {
        const ushort* ap = xs + (size_t)rbase * DK + quad * 128 + m16 * 8;
        #pragma unroll
        for (int mt = 0; mt < 2; ++mt)
            #pragma unroll
            for (int s = 0; s < 4; ++s)
                afr[mt][s] = *(const bf16x8*)(ap + mt * 2048 + s * 512);
    }

    // row labels for this lane's 8 output rows (broadcast int4 loads)
    int rlv[2][4];
    #pragma unroll
    for (int mt = 0; mt < 2; ++mt) {
        int4 v = *(const int4*)(lab + rbase + mt * 16 + quad * 4);
        rlv[mt][0] = v.x; rlv[mt][1] = v.y; rlv[mt][2] = v.z; rlv[mt][3] = v.w;
    }

    float runhp[2][4], runhn[2][4];
    #pragma unroll
    for (int mt = 0; mt < 2; ++mt)
        #pragma unroll
        for (int r = 0; r < 4; ++r) { runhp[mt][r] = -BIGF; runhn[mt][r] = BIGF; }

    bf16x8 bA[8], bB[8];
    float sqA[2], sqB[2];
    int lbA[2], lbB[2];
    f32x4 acc[2][2];

    LOADB(bA, sqA, lbA, 0);

    // 32 chunks of 32 cols (1024-col split); 2-chunk body, indexing static.
    #pragma unroll 1
    for (int k = 0; k < 32; k += 2) {
        LOADB(bB, sqB, lbB, k + 1);         // in flight under MFMA+EPI of bA
        MFMA_CHUNK(bA);
        EPI_CHUNK(sqA, lbA);
        LOADB(bA, sqA, lbA, (k + 2 < 32) ? k + 2 : 31);  // clamped: dead on last
        MFMA_CHUNK(bB);
        EPI_CHUNK(sqB, lbB);
    }

    // reduce across the 16 m16-lanes (cols) sharing each row
    #pragma unroll
    for (int mt = 0; mt < 2; ++mt)
        #pragma unroll
        for (int r = 0; r < 4; ++r) {
            #pragma unroll
            for (int o = 8; o > 0; o >>= 1) {
                runhp[mt][r] = fmaxf(runhp[mt][r], __shfl_xor(runhp[mt][r], o, 16));
                runhn[mt][r] = fminf(runhn[mt][r], __shfl_xor(runhn[mt][r], o, 16));
            }
        }

    if (m16 == 0) {
        #pragma unroll
        for (int mt = 0; mt < 2; ++mt)
            #pragma unroll
            for (int r = 0; r < 4; ++r) {
                int row = rbase + mt * 16 + quad * 4 + r;
                float sqa = sq[row];
                float d2p = fmaxf(sqa + runhp[mt][r], 0.0f);  // == ref's max(d2,0)
                float d2n = fmaxf(sqa + runhn[mt][r], 0.0f);
                atomicMax(&hp_bits[row], __float_as_uint(d2p));
                atomicMax(&hn_comp[row], ~__float_as_uint(d2n));  // min via complement
            }
    }
}

// Kernel 3: per-row loss + grid reduction; last block writes the scalar.
__global__ void finalize_kernel(const unsigned* __restrict__ hp_bits,
                                const unsigned* __restrict__ hn_comp,
                                const int* __restrict__ lab,
                                const unsigned* __restrict__ hist,
                                float* __restrict__ gsum, float* __restrict__ gcnt,
                                unsigned* __restrict__ bcount,
                                float* __restrict__ out, int N)
{
    __shared__ float s_sum[256];
    __shared__ float s_cnt[256];
    int tid = threadIdx.x;
    int row = blockIdx.x * 256 + tid;
    float loss = 0.0f, cv = 0.0f;
    if (row < N) {
        unsigned c = hist[lab[row]];
        bool valid = (c >= 2u) && (c < (unsigned)N);
        if (valid) {
            float dp = sqrtf(__uint_as_float(hp_bits[row]));
            float dn = sqrtf(__uint_as_float(~hn_comp[row]));
            loss = fmaxf(dp - dn + MARGIN, 0.0f);
            cv = 1.0f;
        }
    }
    s_sum[tid] = loss; s_cnt[tid] = cv;
    __syncthreads();
    for (int o = 128; o > 0; o >>= 1) {
        if (tid < o) { s_sum[tid] += s_sum[tid + o]; s_cnt[tid] += s_cnt[tid + o]; }
        __syncthreads();
    }
    if (tid == 0) {
        atomicAdd(gsum, s_sum[0]);
        atomicAdd(gcnt, s_cnt[0]);
        __threadfence();
        unsigned old = atomicAdd(bcount, 1u);
        if (old == gridDim.x - 1) {
            float s = atomicAdd(gsum, 0.0f);   // coherent read
            float c = atomicAdd(gcnt, 0.0f);
            out[0] = (c > 0.0f) ? s / c : 0.0f;
        }
    }
}

extern "C" void kernel_launch(void* const* d_in, const int* in_sizes, int n_in,
                              void* d_out, int out_size, void* d_ws, size_t ws_size,
                              hipStream_t stream) {
    const float* x = (const float*)d_in[0];
    const int* lab = (const int*)d_in[1];
    float* out = (float*)d_out;
    const int N = in_sizes[1];          // 8192

    unsigned* ws = (unsigned*)d_ws;
    unsigned* hist    = ws + WS_HIST;
    unsigned* scal    = ws + WS_GSUM;   // gsum, gcnt, bcount, pad
    float* gsum = (float*)(ws + WS_GSUM);
    float* gcnt = (float*)(ws + WS_GCNT);
    unsigned* bcount = ws + WS_BCNT;
    unsigned* hp_bits = ws + WS_HP;
    unsigned* hn_comp = ws + WS_HN;
    float* sq = (float*)(ws + WS_SQ);
    ushort* xs = (ushort*)(ws + WS_XB);

    prep_kernel<<<N / 32, 256, 0, stream>>>(x, xs, sq, hist, scal, hp_bits, hn_comp, N);
    dim3 grid(N / 128, NSPLIT);
    tile_kernel<<<grid, 256, 0, stream>>>(xs, sq, lab, hist, hp_bits, hn_comp, N);
    finalize_kernel<<<N / 256, 256, 0, stream>>>(hp_bits, hn_comp, lab, hist,
                                                 gsum, gcnt, bcount, out, N);
}